// Round 10
// baseline (131.852 us; speedup 1.0000x reference)
//
#include <hip/hip_runtime.h>

// SpikeEncoder: embedding gather + LayerNorm + LIF scan in FLOAT64
// (harness 'np' reference is f64 — confirmed round 3).
// B=8, S=2048, V=57344, D=1536. Outputs: [spikes (B*S*D), x (B*S*D)] fp32.
//
// Round 10: attack the per-CU memory-request ceiling (U8->U16 was neutral =>
// not prefetch depth). Spec now gathers float2 (2 chains/thread): memory
// instructions per chain halve, stores fuse to 8B, stats LDS read amortizes.
// Plus runtime gamma/beta triviality specialization (bitwise-exact skip of
// *g+b — g=1,b=0 here; t*1.0==t, t+0.0==t, t=-0 unreachable). C=32/W=64
// unchanged. Fixup: {start,end} fused to one double2 load per chunk.

constexpr int Bv = 8, Sv = 2048, Dv = 1536;
constexpr int Cn = 32;              // chunks over S
constexpr int Ln = Sv / Cn;         // 64 steps per chunk
constexpr int Wn = 64;              // warmup steps (merge horizon — keep!)
constexpr int BD = Bv * Dv;         // 12288 chains
constexpr int TNMAX = Ln + Wn;      // 128 rows max per chunk

// ws layout
constexpr size_t FLAG_OFF  = 0;
constexpr size_t STATS_OFF = 64;                                   // 2*B*S doubles
constexpr size_t SE_OFF    = STATS_OFF + (size_t)2 * Bv * Sv * 8;  // {start,end} double2
constexpr size_t WS_NEED   = SE_OFF + (size_t)Cn * BD * 16;

// ---- shared, bit-exact step functions (identical expression trees) ----
__device__ __forceinline__ double ln_x64(float e, double mu, double rs,
                                         double gd, double bd) {
#pragma clang fp contract(off)
    return (((double)e - mu) * rs) * gd + bd;
}
__device__ __forceinline__ double ln_x64_triv(float e, double mu, double rs) {
#pragma clang fp contract(off)
    return ((double)e - mu) * rs;    // == full formula when g=1,b=0 (bitwise)
}
__device__ __forceinline__ double lif_step(double v, double x, bool& spike) {
#pragma clang fp contract(off)
    double vv = v * 0.95;            // separate mul (np rounding)
    vv = vv + x;                     // separate add
    vv = fmin(fmax(vv, -3.0), 3.0);
    spike = (vv >= 1.0);
    return spike ? 0.0 : vv;
}

// ---------------------------------------------------------------------------
// Kernel 0: flags. flag[0] = tok shift (int64 vs int32 buffer detection:
// tokens < 2^31 => int64 data has ALL odd words zero). flag[1] = gamma/beta
// trivial (bitwise gamma==1.0f, beta==+0.0f for all d).
// ---------------------------------------------------------------------------
extern "C" __global__ __launch_bounds__(1024)
void detect_flags(const int* __restrict__ tok,
                  const float* __restrict__ gamma,
                  const float* __restrict__ beta,
                  int* __restrict__ flag)
{
    __shared__ int any_nz, any_gb;
    if (threadIdx.x == 0) { any_nz = 0; any_gb = 0; }
    __syncthreads();
    int nz = 0;
    for (int i = threadIdx.x; i < (Bv * Sv) / 2; i += 1024) nz |= tok[2 * i + 1];
    int bad = 0;
    for (int i = threadIdx.x; i < Dv; i += 1024) {
        bad |= (__float_as_uint(gamma[i]) != 0x3f800000u);
        bad |= (__float_as_uint(beta[i])  != 0u);
    }
    if (nz)  atomicOr(&any_nz, 1);
    if (bad) atomicOr(&any_gb, 1);
    __syncthreads();
    if (threadIdx.x == 0) {
        flag[0] = (any_nz == 0) ? 1 : 0;
        flag[1] = (any_gb == 0) ? 1 : 0;
    }
}

// ---------------------------------------------------------------------------
// Kernel 1: per-row LN stats in f64 (one row per 128-thread block).
// Stores mu,rstd (f64 pair) to stats[], x (f32) to output 1. [unchanged]
// ---------------------------------------------------------------------------
extern "C" __global__ __launch_bounds__(128)
void ln_stats_kernel(const int* __restrict__ tok,
                     const float* __restrict__ emb,
                     const float* __restrict__ gamma,
                     const float* __restrict__ beta,
                     float* __restrict__ x_out,
                     double* __restrict__ stats,
                     const int* __restrict__ tok64_flag)
{
#pragma clang fp contract(off)
    __shared__ double p1[2], p2[2];

    const int row = blockIdx.x;
    const int t   = threadIdx.x;
    const int lane = t & 63, wave = t >> 6;

    const int shift = tok64_flag[0];
    const long long tk = (long long)tok[(size_t)row << shift];
    const float* src = emb + tk * (long long)Dv;

    float4 xv[3];
#pragma unroll
    for (int k = 0; k < 3; ++k) xv[k] = reinterpret_cast<const float4*>(src)[t + 128 * k];

    double s = 0.0;
#pragma unroll
    for (int k = 0; k < 3; ++k) {
        s += (double)xv[k].x; s += (double)xv[k].y;
        s += (double)xv[k].z; s += (double)xv[k].w;
    }
#pragma unroll
    for (int off = 1; off < 64; off <<= 1) s += __shfl_xor(s, off);
    if (lane == 0) p1[wave] = s;
    __syncthreads();
    const double mu = (p1[0] + p1[1]) / 1536.0;

    double q = 0.0;
#pragma unroll
    for (int k = 0; k < 3; ++k) {
        double d0 = (double)xv[k].x - mu; q += d0 * d0;
        double d1 = (double)xv[k].y - mu; q += d1 * d1;
        double d2 = (double)xv[k].z - mu; q += d2 * d2;
        double d3 = (double)xv[k].w - mu; q += d3 * d3;
    }
#pragma unroll
    for (int off = 1; off < 64; off <<= 1) q += __shfl_xor(q, off);
    if (lane == 0) p2[wave] = q;
    __syncthreads();
    const double var  = (p2[0] + p2[1]) / 1536.0;
    const double rstd = 1.0 / sqrt(var + 1e-5);

    if (t == 0) { stats[2 * row] = mu; stats[2 * row + 1] = rstd; }

    float* dst = x_out + (long long)row * Dv;
#pragma unroll
    for (int k = 0; k < 3; ++k) {
        const int f4 = t + 128 * k;
        const float4 g4 = reinterpret_cast<const float4*>(gamma)[f4];
        const float4 b4 = reinterpret_cast<const float4*>(beta)[f4];
        float4 o;
        o.x = (float)((((double)xv[k].x - mu) * rstd) * (double)g4.x + (double)b4.x);
        o.y = (float)((((double)xv[k].y - mu) * rstd) * (double)g4.y + (double)b4.y);
        o.z = (float)((((double)xv[k].z - mu) * rstd) * (double)g4.z + (double)b4.z);
        o.w = (float)((((double)xv[k].w - mu) * rstd) * (double)g4.w + (double)b4.w);
        reinterpret_cast<float4*>(dst)[f4] = o;
    }
}

// ---------------------------------------------------------------------------
// Spec inner body: 2 chains per thread (d0, d0+1), float2 gathers, fused
// 8B NT spike stores. TRIV skips *g+b (bitwise-identical when g=1,b=0).
// ---------------------------------------------------------------------------
template<bool TRIV>
__device__ __forceinline__ void spec_body(
    const float* __restrict__ emb,
    const float* __restrict__ gamma,
    const float* __restrict__ beta,
    const int* __restrict__ tokl,
    const double2* __restrict__ statl,
    int TN, int warm, int sw, int d0,
    float* __restrict__ sp,           // spk + b*Sv*Dv + d0
    double2* __restrict__ se,         // + c*BD + chain0
    double& v0o, double& v1o, double& vs0o, double& vs1o)
{
    double gd0 = 1.0, bd0 = 0.0, gd1 = 1.0, bd1 = 0.0;
    if (!TRIV) {
        const float2 g2 = *reinterpret_cast<const float2*>(&gamma[d0]);
        const float2 b2 = *reinterpret_cast<const float2*>(&beta[d0]);
        gd0 = g2.x; gd1 = g2.y; bd0 = b2.x; bd1 = b2.y;
    }
    constexpr int U = 8;
    float2 ecur[U], enxt[U];
#pragma unroll
    for (int k = 0; k < U; ++k)
        ecur[k] = *reinterpret_cast<const float2*>(&emb[(long long)tokl[k] * Dv + d0]);

    double v0 = 0.0, v1 = 0.0, vs0 = 0.0, vs1 = 0.0;
    for (int i = 0; i < TN; i += U) {
        if (i + U < TN) {
#pragma unroll
            for (int k = 0; k < U; ++k)
                enxt[k] = *reinterpret_cast<const float2*>(
                              &emb[(long long)tokl[i + U + k] * Dv + d0]);
        }
#pragma unroll
        for (int k = 0; k < U; ++k) {
            const int idx = i + k;
            if (idx == warm) { vs0 = v0; vs1 = v1; }
            const double2 st = statl[idx];
            double x0, x1;
            if (TRIV) {
                x0 = ln_x64_triv(ecur[k].x, st.x, st.y);
                x1 = ln_x64_triv(ecur[k].y, st.x, st.y);
            } else {
                x0 = ln_x64(ecur[k].x, st.x, st.y, gd0, bd0);
                x1 = ln_x64(ecur[k].y, st.x, st.y, gd1, bd1);
            }
            bool s0b, s1b;
            v0 = lif_step(v0, x0, s0b);
            v1 = lif_step(v1, x1, s1b);
            if (idx >= warm) {
                union { float2 f2; double d8; } u;
                u.f2.x = s0b ? 1.0f : 0.0f;
                u.f2.y = s1b ? 1.0f : 0.0f;
                __builtin_nontemporal_store(
                    u.d8, reinterpret_cast<double*>(&sp[(size_t)(sw + idx) * Dv]));
            }
        }
#pragma unroll
        for (int k = 0; k < U; ++k) ecur[k] = enxt[k];
    }
    v0o = v0; v1o = v1; vs0o = vs0; vs1o = vs1;
}

// ---------------------------------------------------------------------------
// Kernel 2a: speculative LIF chunks. Grid = B * Cn * (D/512) = 768 blocks
// x 256 threads; thread owns chains (d0, d0+1). LDS-staged row metadata.
// ---------------------------------------------------------------------------
extern "C" __global__ __launch_bounds__(256)
void lif64_spec(const int* __restrict__ tok,
                const float* __restrict__ emb,
                const float* __restrict__ gamma,
                const float* __restrict__ beta,
                const double* __restrict__ stats,
                float* __restrict__ spk,
                double2* __restrict__ se,
                const int* __restrict__ flags)
{
    constexpr int DBLK = Dv / 512;            // 3
    __shared__ int     tokl[TNMAX];
    __shared__ double2 statl[TNMAX];

    const int t    = threadIdx.x;
    const int bid  = blockIdx.x;
    const int dblk = bid % DBLK;
    const int c    = (bid / DBLK) % Cn;
    const int b    = bid / (DBLK * Cn);
    const int d0   = dblk * 512 + 2 * t;

    const int s0 = c * Ln;
    const int sw = (c == 0) ? 0 : s0 - Wn;
    const int TN = s0 + Ln - sw;              // 64 or 128
    const int warm = s0 - sw;                 // 0 or 64
    const int rowbase = b * Sv;

    if (t < TN) {
        const int row = rowbase + sw + t;
        const int shift = flags[0];
        tokl[t]  = tok[(size_t)row << shift];                     // token (< 2^31)
        statl[t] = reinterpret_cast<const double2*>(stats)[row];  // {mu, rstd}
    }
    __syncthreads();

    float* sp = spk + (size_t)b * Sv * Dv + d0;
    double v0, v1, vs0, vs1;
    if (flags[1]) {
        spec_body<true >(emb, gamma, beta, tokl, statl, TN, warm, sw, d0, sp,
                         se, v0, v1, vs0, vs1);
    } else {
        spec_body<false>(emb, gamma, beta, tokl, statl, TN, warm, sw, d0, sp,
                         se, v0, v1, vs0, vs1);
    }

    const size_t chain0 = (size_t)b * Dv + d0;
    double2 a; a.x = vs0; a.y = v0;
    double2 bq; bq.x = vs1; bq.y = v1;
    se[(size_t)c * BD + chain0]     = a;
    se[(size_t)c * BD + chain0 + 1] = bq;
}

// ---------------------------------------------------------------------------
// Kernel 2b: exact fixup. One thread per chain. One double2 {start,end} load
// per chunk; bitwise-equal entry => chunk provably exact, jump via exit;
// else recompute chunk (8-deep prefetch, full formula — bitwise-equivalent).
// ---------------------------------------------------------------------------
extern "C" __global__ __launch_bounds__(64)
void lif64_fixup(const int* __restrict__ tok,
                 const float* __restrict__ emb,
                 const float* __restrict__ gamma,
                 const float* __restrict__ beta,
                 const double* __restrict__ stats,
                 const double2* __restrict__ se,
                 float* __restrict__ spk,
                 const int* __restrict__ flags)
{
    const int gid = blockIdx.x * 64 + threadIdx.x;   // chain id
    const int b = gid / Dv;
    const int d = gid - b * Dv;
    const int shift = flags[0];
    const double gd = (double)gamma[d];
    const double bd = (double)beta[d];
    const int rowbase = b * Sv;
    float* sp = spk + (size_t)b * Sv * Dv + d;

    double v = 0.0;
    for (int c = 0; c < Cn; ++c) {
        const double2 sec = se[(size_t)c * BD + gid];
        if (v == sec.x) { v = sec.y; continue; }
        // recompute chunk c (rare): 8-deep prefetched
        constexpr int U = 8;
        const int s0 = c * Ln;
        float  ecur[U], enxt[U];
        double mcur[U], mnxt[U], rcur[U], rnxt[U];
#pragma unroll
        for (int k = 0; k < U; ++k) {
            const int row = rowbase + s0 + k;
            const long long tk = (long long)tok[(size_t)row << shift];
            ecur[k] = emb[tk * (long long)Dv + d];
            mcur[k] = stats[2 * row];
            rcur[k] = stats[2 * row + 1];
        }
        for (int i = 0; i < Ln; i += U) {
            if (i + U < Ln) {
#pragma unroll
                for (int k = 0; k < U; ++k) {
                    const int row = rowbase + s0 + i + U + k;
                    const long long tk = (long long)tok[(size_t)row << shift];
                    enxt[k] = emb[tk * (long long)Dv + d];
                    mnxt[k] = stats[2 * row];
                    rnxt[k] = stats[2 * row + 1];
                }
            }
#pragma unroll
            for (int k = 0; k < U; ++k) {
                const double x = ln_x64(ecur[k], mcur[k], rcur[k], gd, bd);
                bool spike;
                v = lif_step(v, x, spike);
                sp[(size_t)(s0 + i + k) * Dv] = spike ? 1.0f : 0.0f;
            }
#pragma unroll
            for (int k = 0; k < U; ++k) {
                ecur[k] = enxt[k]; mcur[k] = mnxt[k]; rcur[k] = rnxt[k];
            }
        }
    }
}

// ---------------------------------------------------------------------------
// Fallback: sequential LIF (round-3 version, bit-identical step math).
// Used only if ws is too small for the speculative state arrays.
// ---------------------------------------------------------------------------
extern "C" __global__ __launch_bounds__(64)
void lif64_seq(const int* __restrict__ tok,
               const float* __restrict__ emb,
               const float* __restrict__ gamma,
               const float* __restrict__ beta,
               const double* __restrict__ stats,
               float* __restrict__ spk,
               const int* __restrict__ flags)
{
    const int gid = blockIdx.x * 64 + threadIdx.x;
    const int b = gid / Dv;
    const int d = gid - b * Dv;
    const int shift = flags[0];
    const int rowbase = b * Sv;
    const double gd = (double)gamma[d];
    const double bd = (double)beta[d];
    float* sp = spk + (size_t)b * Sv * Dv + d;

    constexpr int U = 8;
    float  ecur[U], enxt[U];
    double mcur[U], mnxt[U], rcur[U], rnxt[U];
#pragma unroll
    for (int k = 0; k < U; ++k) {
        const int row = rowbase + k;
        const long long tk = (long long)tok[(size_t)row << shift];
        ecur[k] = emb[tk * (long long)Dv + d];
        mcur[k] = stats[2 * row];
        rcur[k] = stats[2 * row + 1];
    }
    double v = 0.0;
    for (int s = 0; s < Sv; s += U) {
        if (s + U < Sv) {
#pragma unroll
            for (int k = 0; k < U; ++k) {
                const int row = rowbase + s + U + k;
                const long long tk = (long long)tok[(size_t)row << shift];
                enxt[k] = emb[tk * (long long)Dv + d];
                mnxt[k] = stats[2 * row];
                rnxt[k] = stats[2 * row + 1];
            }
        }
#pragma unroll
        for (int k = 0; k < U; ++k) {
            const double x = ln_x64(ecur[k], mcur[k], rcur[k], gd, bd);
            bool spike;
            v = lif_step(v, x, spike);
            __builtin_nontemporal_store(spike ? 1.0f : 0.0f, &sp[(size_t)(s + k) * Dv]);
        }
#pragma unroll
        for (int k = 0; k < U; ++k) { ecur[k] = enxt[k]; mcur[k] = mnxt[k]; rcur[k] = rnxt[k]; }
    }
}

extern "C" void kernel_launch(void* const* d_in, const int* in_sizes, int n_in,
                              void* d_out, int out_size, void* d_ws, size_t ws_size,
                              hipStream_t stream)
{
    const int*   tok   = (const int*)  d_in[0];
    const float* emb   = (const float*)d_in[1];
    const float* gamma = (const float*)d_in[2];
    const float* beta  = (const float*)d_in[3];

    float* out = (float*)d_out;
    float* spk = out;                               // output 0: spikes
    float* x   = out + (size_t)Bv * Sv * Dv;        // output 1: x (LN result)

    int*    flg   = (int*)((char*)d_ws + FLAG_OFF);
    double* stats = (double*)((char*)d_ws + STATS_OFF);

    detect_flags<<<1, 1024, 0, stream>>>(tok, gamma, beta, flg);
    ln_stats_kernel<<<Bv * Sv, 128, 0, stream>>>(tok, emb, gamma, beta, x, stats, flg);

    if (ws_size >= WS_NEED) {
        double2* se = (double2*)((char*)d_ws + SE_OFF);
        lif64_spec<<<Bv * Cn * (Dv / 512), 256, 0, stream>>>(
            tok, emb, gamma, beta, stats, spk, se, flg);
        lif64_fixup<<<BD / 64, 64, 0, stream>>>(
            tok, emb, gamma, beta, stats, se, spk, flg);
    } else {
        lif64_seq<<<BD / 64, 64, 0, stream>>>(tok, emb, gamma, beta, stats, spk, flg);
    }
}